// Round 1
// baseline (157.200 us; speedup 1.0000x reference)
//
#include <hip/hip_runtime.h>
#include <math.h>

// R1: atomic-free split-K (partial buffers reduced in consumers), 2x K-split
//     on both GEMMs for occupancy, LDS-transposed coalesced final stores,
//     accumulator zero-pass removed.

// Problem constants
#define B64 64
#define IN_SH 10000
#define EXP_SH 53
#define HID 1500
#define NPAD1 1536          // padded N for gemm1 partials
#define NBC 2048
#define K2 1553
#define KS1 40              // split-K chunks gemm1 (24*40 = 960 gemm blocks)
#define KST1 8              // 8 steps of 32 => kchunk 256 (40*256 = 10240 = padded K)
#define KS2 13              // 13*128 = 1664 >= 1553
#define KST2 4              // 4 steps of 32 => kchunk 128
#define XSTEP 56            // Xf k-steps (1792/32), zero-padded past 1553
#define CMCH 32             // colmax row chunks
#define CMBLK 256           // colmax blocks (8 j-tiles x 32 row-chunks)
#define WLDS 640            // dwords per wave LDS buffer (32 rows * 20)
#define ACC1 (NPAD1 * 64)   // 98304 floats per gemm1 partial
#define ACC2 (NBC * 64)     // 131072 floats per gemm2 partial

using short8  = __attribute__((ext_vector_type(8))) short;
using floatx4 = __attribute__((ext_vector_type(4))) float;
using uintx4  = __attribute__((ext_vector_type(4))) unsigned int;
using uintx2  = __attribute__((ext_vector_type(2))) unsigned int;

__device__ __forceinline__ unsigned short f2bf(float f) {
    unsigned u = __float_as_uint(f);
    u += 0x7fffu + ((u >> 16) & 1u);   // RNE
    return (unsigned short)(u >> 16);
}

// B-fragment order (per 32-k step):
//   frag[(step*4 + sgrp)*64 + lane][j] = act[b = sgrp*16 + (lane&15)][k = step*32 + (lane>>4)*8 + j]

// Node 1: build gosBf only (no accumulator zeroing needed anymore).
__global__ __launch_bounds__(256) void prep_k(const float* __restrict__ g,
                                              unsigned short* __restrict__ gosBf) {
    int t    = blockIdx.x * 256 + threadIdx.x;   // [0, 81920)
    int lane = t & 63;
    int sgrp = (t >> 6) & 3;
    int step = t >> 8;                           // [0, 320)
    int q    = lane >> 4;
    int l15  = lane & 15;
    int b    = sgrp * 16 + l15;
    int k0   = step * 32 + q * 8;
    const float* p = g + (size_t)b * IN_SH + k0;
    unsigned int o[4];
    #pragma unroll
    for (int i = 0; i < 4; i++) {
        float lo = (k0 + 2 * i     < IN_SH) ? p[2 * i]     : 0.f;
        float hi = (k0 + 2 * i + 1 < IN_SH) ? p[2 * i + 1] : 0.f;
        o[i] = (unsigned)f2bf(lo) | ((unsigned)f2bf(hi) << 16);
    }
    uintx4 v; v.x = o[0]; v.y = o[1]; v.z = o[2]; v.w = o[3];
    *(uintx4*)(gosBf + (size_t)t * 8) = v;
}

__device__ __forceinline__ void load_b4(const unsigned short* __restrict__ bf,
                                        int stg, uintx4 bv[4]) {
    #pragma unroll
    for (int s = 0; s < 4; s++)
        bv[s] = *(const uintx4*)(bf + (size_t)(stg * 4 + s) * 512);
}

// Barrier-free MFMA GEMM core. Each wave stages its own 16-column W sub-tile
// into a wave-private LDS double buffer (intra-wave DS ops are in-order ->
// no __syncthreads in the K-loop). R1: plain stores into a per-K-chunk
// partial buffer (pbuf already offset by caller) -- no atomics.
template<int KSTEPS>
__device__ __forceinline__ void gemm_core(
    const float* __restrict__ W, const unsigned short* __restrict__ Bfc,
    float* __restrict__ pbuf, int N, int K, int ldw, int bx, int by, int tid,
    float* __restrict__ ldsw)   // this wave's 2*WLDS-dword region
{
    int lane = tid & 63;
    int q    = lane >> 4;
    int l15  = lane & 15;
    int n0   = bx * 64 + 16 * (tid >> 6);   // this wave's 16 columns
    int k0   = by * (KSTEPS * 32);
    bool fast = (n0 + 16 <= N) && (k0 + KSTEPS * 32 <= K);
    int kl  = lane >> 2;                    // 0..15  (staging row)
    int c4  = (lane & 3) * 4;               // staging col offset

    const unsigned short* bf = Bfc + (size_t)lane * 8;

    floatx4 acc[4];
    #pragma unroll
    for (int s = 0; s < 4; s++) acc[s] = (floatx4){0.f, 0.f, 0.f, 0.f};

    floatx4 g[2][2];   // [stage parity][row half]

    #define GLB(st, slot)                                                        \
        {                                                                        \
            int kb_ = k0 + (st) * 32;                                            \
            _Pragma("unroll")                                                    \
            for (int i_ = 0; i_ < 2; i_++) {                                     \
                int kg_ = kb_ + kl + 16 * i_;                                    \
                if (fast) {                                                      \
                    g[slot][i_] = *(const floatx4*)(W + (size_t)kg_ * ldw + n0 + c4); \
                } else {                                                         \
                    _Pragma("unroll")                                            \
                    for (int j_ = 0; j_ < 4; j_++)                               \
                        g[slot][i_][j_] = (kg_ < K && n0 + c4 + j_ < N)          \
                            ? W[(size_t)kg_ * ldw + n0 + c4 + j_] : 0.f;         \
                }                                                                \
            }                                                                    \
        }
    #define LWR(buf, slot)                                                       \
        {                                                                        \
            _Pragma("unroll")                                                    \
            for (int i_ = 0; i_ < 2; i_++)                                       \
                *(floatx4*)(ldsw + (buf) * WLDS + (kl + 16 * i_) * 20 + c4) = g[slot][i_]; \
        }

    GLB(0, 0);
    if (KSTEPS > 1) GLB(1, 1);
    LWR(0, 0);

    uintx4 bv[2][4];
    load_b4(bf, 0, bv[0]);
    if (KSTEPS > 1) load_b4(bf, 1, bv[1]);

    #pragma unroll
    for (int st = 0; st < KSTEPS; st++) {
        const int s = st & 1;                     // compile-time after unroll
        const float* lb = ldsw + s * WLDS;

        short8 af;
        #pragma unroll
        for (int j = 0; j < 8; j++)
            af[j] = (short)f2bf(lb[(q * 8 + j) * 20 + l15]);

        uintx4 bt[4];
        if (st + 2 < KSTEPS) {
            GLB(st + 2, s);
            load_b4(bf, st + 2, bt);
        }

        #pragma unroll
        for (int m = 0; m < 4; m++) {
            short8 bf8 = __builtin_bit_cast(short8, bv[s][m]);
            acc[m] = __builtin_amdgcn_mfma_f32_16x16x32_bf16(af, bf8, acc[m], 0, 0, 0);
        }

        if (st + 1 < KSTEPS) LWR(1 - s, 1 - s);
        if (st + 2 < KSTEPS) {
            #pragma unroll
            for (int m = 0; m < 4; m++) bv[s][m] = bt[m];
        }
    }
    #undef GLB
    #undef LWR

    // D lane mapping: col=lane&15 (batch within group s), row=q*4+r (n offset)
    int nrow = n0 + q * 4;
    #pragma unroll
    for (int s = 0; s < 4; s++) {
        #pragma unroll
        for (int rr = 0; rr < 4; rr++)
            pbuf[(size_t)(nrow + rr) * 64 + s * 16 + l15] = acc[s][rr];
    }
}

// Node 2: [0,256) hpo colmax FIRST (resident from t=0, streams in gemm1's BW
// slack, retires early); [256,1216) GEMM1 partials  hpre_p[by] = gos @ W1 chunk.
__global__ __launch_bounds__(256) void gemm1_k(
    const float* __restrict__ W1, const unsigned short* __restrict__ gosBf,
    float* __restrict__ hpre_p, const float* __restrict__ M, float* __restrict__ cm)
{
    __shared__ float lds[4 * 2 * WLDS];
    int bi = blockIdx.x;
    if (bi < CMBLK) {
        int j  = (bi & 7) * 256 + threadIdx.x;   // 0..2047
        int i0 = (bi >> 3) * 64;
        float m = 0.0f;
        #pragma unroll 16
        for (int i = i0; i < i0 + 64; i++)
            m = fmaxf(m, M[(size_t)i * NBC + j]);
        cm[(bi >> 3) * NBC + j] = m;
    } else {
        int gb = bi - CMBLK;                     // [0, 960)
        int bx = gb % 24;
        int by = gb / 24;
        gemm_core<KST1>(W1, gosBf + (size_t)by * (KST1 * 4) * 512,
                        hpre_p + (size_t)by * ACC1, HID, IN_SH, HID, bx, by,
                        threadIdx.x, lds + (threadIdx.x >> 6) * (2 * WLDS));
    }
}

// Node 4: GEMM2 partials  logits_p[by] = X @ W2 chunk  (N=2048, K=1553 padded)
__global__ __launch_bounds__(256) void gemm2_k(
    const float* __restrict__ W2, const unsigned short* __restrict__ Xf,
    float* __restrict__ logits_p)
{
    __shared__ float lds[4 * 2 * WLDS];
    gemm_core<KST2>(W2, Xf + (size_t)blockIdx.y * (KST2 * 4) * 512,
                    logits_p + (size_t)blockIdx.y * ACC2, NBC, K2, NBC,
                    blockIdx.x, blockIdx.y,
                    threadIdx.x, lds + (threadIdx.x >> 6) * (2 * WLDS));
}

// Node 3: [0,112) reduce 40 gemm1 partials + bias + exact GELU, concat exp_x,
// emit Xf (B-fragment order, zero-padded to 1792); each block = half a k-step.
// [112,120) reduce cm's 32 chunks -> cmr[2048].
__global__ __launch_bounds__(256) void combine1(
    const float* __restrict__ hpre_p, const float* __restrict__ b1,
    const float* __restrict__ expx, unsigned short* __restrict__ Xf,
    const float* __restrict__ cm, float* __restrict__ cmr)
{
    int bi = blockIdx.x;
    if (bi < 2 * XSTEP) {
        int step = bi >> 1, half = bi & 1;
        int tid  = threadIdx.x;
        int lane = tid & 63;
        int sgrp = tid >> 6;
        int q    = lane >> 4;
        int l15  = lane & 15;
        int b    = sgrp * 16 + l15;
        int kb   = step * 32 + q * 8;
        int nb   = kb + half * 4;        // this thread's 4 consecutive n values
        float sv[4];
        if (nb + 3 < HID) {
            // fast path: 4 parallel accumulator chains, ks-interleaved for MLP
            float s0 = b1[nb], s1 = b1[nb + 1], s2 = b1[nb + 2], s3 = b1[nb + 3];
            const float* p = hpre_p + (size_t)nb * 64 + b;
            #pragma unroll 8
            for (int ks = 0; ks < KS1; ks++, p += ACC1) {
                s0 += p[0]; s1 += p[64]; s2 += p[128]; s3 += p[192];
            }
            sv[0] = s0; sv[1] = s1; sv[2] = s2; sv[3] = s3;
            #pragma unroll
            for (int jj = 0; jj < 4; jj++)
                sv[jj] = 0.5f * sv[jj] * (1.0f + erff(sv[jj] * 0.70710678118654752f));
        } else {
            #pragma unroll
            for (int jj = 0; jj < 4; jj++) {
                int n = nb + jj;
                float v = 0.f;
                if (n < HID) {
                    float s = b1[n];
                    for (int ks = 0; ks < KS1; ks++)
                        s += hpre_p[(size_t)ks * ACC1 + (size_t)n * 64 + b];
                    v = 0.5f * s * (1.0f + erff(s * 0.70710678118654752f));
                } else if (n < HID + EXP_SH) {
                    v = expx[b * EXP_SH + (n - HID)];
                }
                sv[jj] = v;
            }
        }
        unsigned int o0 = (unsigned)f2bf(sv[0]) | ((unsigned)f2bf(sv[1]) << 16);
        unsigned int o1 = (unsigned)f2bf(sv[2]) | ((unsigned)f2bf(sv[3]) << 16);
        size_t t = (size_t)step * 256 + tid;
        uintx2 v; v.x = o0; v.y = o1;
        *(uintx2*)(Xf + t * 8 + half * 4) = v;
    } else {
        int j = (bi - 2 * XSTEP) * 256 + threadIdx.x;   // 0..2047
        float m = 0.f;
        #pragma unroll
        for (int c = 0; c < CMCH; c++) m = fmaxf(m, cm[c * NBC + j]);
        cmr[j] = m;
    }
}

// Node 5: reduce 13 gemm2 partials + bias + sigmoid, multiply by colmax;
// LDS 32x65 transpose tile so out-writes are 128B-contiguous per batch row.
__global__ __launch_bounds__(256) void final_k(
    const float* __restrict__ logits_p, const float* __restrict__ b2,
    const float* __restrict__ cmr, float* __restrict__ out)
{
    __shared__ float lds[32 * 65];
    int j0  = blockIdx.x * 32;
    int tid = threadIdx.x;
    #pragma unroll
    for (int e = 0; e < 8; e++) {
        int lin = e * 256 + tid;            // 0..2047  (j-major, b-minor)
        int jj  = lin >> 6;
        int b   = lin & 63;
        int j   = j0 + jj;
        float s = b2[j];
        const float* p = logits_p + (size_t)j * 64 + b;
        #pragma unroll
        for (int ks = 0; ks < KS2; ks++)
            s += p[(size_t)ks * ACC2];
        float sig = 1.0f / (1.0f + expf(-s));
        lds[jj * 65 + b] = sig * cmr[j];
    }
    __syncthreads();
    #pragma unroll
    for (int e = 0; e < 8; e++) {
        int lin = e * 256 + tid;            // 0..2047  (b-major, j-minor)
        int b   = lin >> 5;
        int jj  = lin & 31;
        out[(size_t)b * NBC + j0 + jj] = lds[jj * 65 + b];
    }
}

extern "C" void kernel_launch(void* const* d_in, const int* in_sizes, int n_in,
                              void* d_out, int out_size, void* d_ws, size_t ws_size,
                              hipStream_t stream) {
    const float* gos  = (const float*)d_in[0];
    const float* expx = (const float*)d_in[1];
    const float* W1   = (const float*)d_in[2];
    const float* b1   = (const float*)d_in[3];
    const float* W2   = (const float*)d_in[4];
    const float* b2   = (const float*)d_in[5];
    const float* hpo  = (const float*)d_in[6];
    float* out = (float*)d_out;

    // workspace layout (16B-aligned offsets)
    char* ws = (char*)d_ws;
    unsigned short* gosBf = (unsigned short*)ws;                   // 1,310,720
    unsigned short* Xf    = (unsigned short*)(ws + 1310720);       //   229,376
    float* cm       = (float*)(ws + 1540096);                      //   262,144
    float* cmr      = (float*)(ws + 1802240);                      //     8,192
    float* hpre_p   = (float*)(ws + 1810432);                      // 40*393,216 = 15,728,640
    float* logits_p = (float*)(ws + 17539072);                     // 13*524,288 =  6,815,744
    // total ~24.4 MB

    // 1) build gosBf (no zeroing pass needed -- partials are write-only)
    prep_k<<<320, 256, 0, stream>>>(gos, gosBf);

    // 2) hpo colmax (first 256 blocks) + GEMM1 partials (KS1=40, atomic-free)
    gemm1_k<<<CMBLK + 24 * KS1, 256, 0, stream>>>(W1, gosBf, hpre_p, hpo, cm);

    // 3) reduce partials + bias + gelu + concat exp_x -> Xf | reduce cm -> cmr
    combine1<<<2 * XSTEP + 8, 256, 0, stream>>>(hpre_p, b1, expx, Xf, cm, cmr);

    // 4) GEMM2 partials (KS2=13, atomic-free)
    gemm2_k<<<dim3(NBC / 64, KS2), 256, 0, stream>>>(W2, Xf, logits_p);

    // 5) reduce partials + bias + sigmoid + *cmr -> out (coalesced via LDS)
    final_k<<<NBC / 32, 256, 0, stream>>>(logits_p, b2, cmr, out);
}